// Round 13
// baseline (127.330 us; speedup 1.0000x reference)
//
#include <hip/hip_runtime.h>
#include <math.h>

#define BN 4096
#define DD 128
#define NWT 64                       // 64-row panels
#define NTILES (NWT * (NWT + 1) / 2) // 2080 upper-tri 64x64 tiles
#define NJB 64                       // nes partials per row (j-panel count)
#define SLOTS 1024                   // per-tile record slots (expect ~64)
#define OVCAP (4u * 1024u * 1024u)

typedef __attribute__((ext_vector_type(8))) short short8;
typedef __attribute__((ext_vector_type(4))) float f32x4;

__device__ __forceinline__ unsigned short f2bf(float f) {
    unsigned int u = __float_as_uint(f);
    u += 0x7FFFu + ((u >> 16) & 1u);   // RNE; inputs are finite normals
    return (unsigned short)(u >> 16);
}

// ws layout (8/16-aligned):
//   sbf[BN*DD] bf16 | mag[BN] f32 | nes_part[NJB][BN] f32 | nes[BN] f32 |
//   part_sum[NTILES] f32 | part_cnt[NTILES] u32 | tilecnt[NTILES] i32 |
//   ovcnt u32 (+pad 16 words) | recs[NTILES*SLOTS] uint2 | ovrecs[OVCAP] uint2

__global__ __launch_bounds__(256)
void prep_kernel(const float* __restrict__ score, unsigned short* __restrict__ sbf,
                 float* __restrict__ mag) {
    int row  = blockIdx.x * 4 + (threadIdx.x >> 6);
    int lane = threadIdx.x & 63;
    float2 v = *reinterpret_cast<const float2*>(score + (size_t)row * DD + lane * 2);
    float s = v.x * v.x + v.y * v.y;
    #pragma unroll
    for (int off = 32; off; off >>= 1) s += __shfl_xor(s, off);
    ushort2 u; u.x = f2bf(v.x); u.y = f2bf(v.y);
    *reinterpret_cast<ushort2*>(sbf + (size_t)row * DD + lane * 2) = u;
    if (lane == 0) mag[row] = s;
}

// ONE WAVE per 64x64 tile: 2080 fully independent waves, no LDS, no barriers,
// no atomics (ballot-compacted record emission into per-tile slot ranges).
// All 32 fragments loaded up-front (static unroll) so a single latency stall
// covers every gather; then 64 MFMAs; then the masked-exp epilogue.
__global__ __launch_bounds__(256)
void nes_kernel(const unsigned short* __restrict__ sbf, const int* __restrict__ target,
                const float* __restrict__ alphap, const float* __restrict__ mag,
                float* __restrict__ nes_part,
                uint2* __restrict__ recs, uint2* __restrict__ ovrecs,
                int* __restrict__ tilecnt, unsigned int* __restrict__ ovcnt) {
    const int tid = threadIdx.x;
    const int w = tid >> 6, lane = tid & 63;
    const int lhi = lane >> 4, llo = lane & 15;
    const int t = blockIdx.x * 4 + w;      // 520 blocks x 4 waves = 2080
    if (t >= NTILES) return;

    // decode t -> (ib <= jb)
    int ib = 0, rem = t, rl = NWT;
    while (rem >= rl) { rem -= rl; ++ib; --rl; }
    const int jb = ib + rem;
    const int i0 = ib * 64, j0 = jb * 64;
    const bool diag = (ib == jb);

    // ---- load all fragments (a[m][kk], b[n][kk]) ----
    short8 a[4][4], b[4][4];
    #pragma unroll
    for (int m = 0; m < 4; ++m)
        #pragma unroll
        for (int kk = 0; kk < 4; ++kk)
            a[m][kk] = *reinterpret_cast<const short8*>(
                sbf + (size_t)(i0 + m * 16 + llo) * DD + kk * 32 + lhi * 8);
    #pragma unroll
    for (int n = 0; n < 4; ++n)
        #pragma unroll
        for (int kk = 0; kk < 4; ++kk)
            b[n][kk] = *reinterpret_cast<const short8*>(
                sbf + (size_t)(j0 + n * 16 + llo) * DD + kk * 32 + lhi * 8);

    // ---- 64 MFMAs ----
    f32x4 acc[4][4] = {};
    #pragma unroll
    for (int kk = 0; kk < 4; ++kk)
        #pragma unroll
        for (int m = 0; m < 4; ++m)
            #pragma unroll
            for (int n = 0; n < 4; ++n)
                acc[m][n] = __builtin_amdgcn_mfma_f32_16x16x32_bf16(a[m][kk], b[n][kk], acc[m][n], 0, 0, 0);

    // ---- epilogue (C/D: col = lane&15, row = lhi*4+reg) ----
    const float alpha = alphap[0];
    float mj[4]; int tj[4]; int jj[4];
    #pragma unroll
    for (int n = 0; n < 4; ++n) {
        int j = j0 + n * 16 + llo;
        jj[n] = j; mj[n] = mag[j]; tj[n] = target[j];
    }
    float cs[4] = {0.f, 0.f, 0.f, 0.f};
    unsigned int wbase = 0;                 // wave-uniform running record count
    #pragma unroll
    for (int m = 0; m < 4; ++m) {
        #pragma unroll
        for (int rg = 0; rg < 4; ++rg) {
            int i = i0 + m * 16 + lhi * 4 + rg;
            float mi = mag[i];
            int ti = target[i];
            float rs = 0.f;
            #pragma unroll
            for (int n = 0; n < 4; ++n) {
                float d2 = fmaxf(mi + mj[n] - 2.0f * acc[m][n][rg], 0.0f);
                float dist = sqrtf(d2);
                bool p = (ti == tj[n]);
                float e = p ? 0.0f : __expf(alpha - dist);
                rs += e;
                cs[n] += e;
                bool emit = p && (jj[n] > i);
                unsigned long long mask = __ballot(emit);
                if (emit) {
                    unsigned pos = (unsigned)__popcll(mask & ((1ULL << lane) - 1ULL));
                    unsigned slot = wbase + pos;
                    uint2 r;
                    r.x = __float_as_uint(dist);
                    r.y = ((unsigned)i << 16) | (unsigned)jj[n];
                    if (slot < SLOTS) recs[(size_t)t * SLOTS + slot] = r;
                    else {
                        unsigned o = atomicAdd(ovcnt, 1u);
                        if (o < OVCAP) ovrecs[o] = r;
                    }
                }
                wbase += (unsigned)__popcll(mask);
            }
            rs += __shfl_xor(rs, 1);
            rs += __shfl_xor(rs, 2);
            rs += __shfl_xor(rs, 4);
            rs += __shfl_xor(rs, 8);
            if (llo == 0) nes_part[(size_t)jb * BN + i] = rs;   // row partial
        }
    }
    #pragma unroll
    for (int n = 0; n < 4; ++n) {
        cs[n] += __shfl_xor(cs[n], 16);
        cs[n] += __shfl_xor(cs[n], 32);
        if (!diag && lane < 16)
            nes_part[(size_t)ib * BN + jj[n]] = cs[n];          // col partial
    }
    if (lane == 0) tilecnt[t] = (int)wbase;
}

__global__ __launch_bounds__(256)
void nes_reduce_kernel(const float* __restrict__ nes_part, float* __restrict__ nes) {
    int t = blockIdx.x * 256 + threadIdx.x;   // 0..BN-1
    float s = 0.f;
    #pragma unroll
    for (int k = 0; k < NJB; ++k) s += nes_part[(size_t)k * BN + t];
    nes[t] = s;
}

// map over emitted records: log(nes_i + nes_j) + dist -> relu -> square.
__global__ __launch_bounds__(256)
void pos_kernel(const uint2* __restrict__ recs, const uint2* __restrict__ ovrecs,
                const int* __restrict__ tilecnt, const unsigned int* __restrict__ ovcnt,
                const float* __restrict__ nes,
                float* __restrict__ part_sum, unsigned int* __restrict__ part_cnt) {
    __shared__ float ssum[4];
    __shared__ unsigned int scnt[4];
    const int t = blockIdx.x;
    const int tid = threadIdx.x;
    const int w = tid >> 6;
    int cnt = tilecnt[t];
    if (cnt > SLOTS) cnt = SLOTS;
    float s = 0.f;
    unsigned int cc = 0;
    for (int k = tid; k < cnt; k += 256) {
        uint2 r = recs[(size_t)t * SLOTS + k];
        float dist = __uint_as_float(r.x);
        int i = r.y >> 16, j = r.y & 0xFFFF;
        float tv = __logf(nes[i] + nes[j]) + dist;
        if (tv > 0.f) s += tv * tv;
        cc++;
    }
    unsigned int oc = *ovcnt;
    if (oc > OVCAP) oc = OVCAP;
    for (unsigned int k = (unsigned)t * 256u + tid; k < oc; k += (unsigned)NTILES * 256u) {
        uint2 r = ovrecs[k];
        float dist = __uint_as_float(r.x);
        int i = r.y >> 16, j = r.y & 0xFFFF;
        float tv = __logf(nes[i] + nes[j]) + dist;
        if (tv > 0.f) s += tv * tv;
        cc++;
    }
    #pragma unroll
    for (int off = 1; off < 64; off <<= 1) {
        s += __shfl_xor(s, off);
        cc += __shfl_xor(cc, off);
    }
    if ((tid & 63) == 0) { ssum[w] = s; scnt[w] = cc; }
    __syncthreads();
    if (tid == 0) {
        part_sum[t] = ssum[0] + ssum[1] + ssum[2] + ssum[3];
        part_cnt[t] = scnt[0] + scnt[1] + scnt[2] + scnt[3];
    }
}

__global__ __launch_bounds__(256)
void finalize_kernel(const float* __restrict__ part_sum,
                     const unsigned int* __restrict__ part_cnt,
                     float* __restrict__ out) {
    __shared__ float fs[4];
    __shared__ unsigned int fc[4];
    int tid = threadIdx.x;
    float s = 0.f;
    unsigned int c = 0;
    #pragma unroll
    for (int k = 0; k < 9; ++k) {
        int idx = k * 256 + tid;
        if (idx < NTILES) {
            s += part_sum[idx];
            c += part_cnt[idx];
        }
    }
    #pragma unroll
    for (int off = 1; off < 64; off <<= 1) {
        s += __shfl_xor(s, off);
        c += __shfl_xor(c, off);
    }
    if ((tid & 63) == 0) { fs[tid >> 6] = s; fc[tid >> 6] = c; }
    __syncthreads();
    if (tid == 0) {
        float S = fs[0] + fs[1] + fs[2] + fs[3];
        float C = (float)(fc[0] + fc[1] + fc[2] + fc[3]);
        out[0] = S / (2.0f * C);
    }
}

extern "C" void kernel_launch(void* const* d_in, const int* in_sizes, int n_in,
                              void* d_out, int out_size, void* d_ws, size_t ws_size,
                              hipStream_t stream) {
    const float* score  = (const float*)d_in[0];
    const int*   target = (const int*)d_in[1];
    const float* alpha  = (const float*)d_in[2];
    float* out = (float*)d_out;

    unsigned short* sbf = (unsigned short*)d_ws;
    float* mag      = (float*)((char*)d_ws + (size_t)BN * DD * 2);
    float* nes_part = mag + BN;
    float* nes      = nes_part + (size_t)NJB * BN;
    float* part_sum = nes + BN;
    unsigned int* part_cnt = (unsigned int*)(part_sum + NTILES);
    int* tilecnt    = (int*)(part_cnt + NTILES);
    unsigned int* ovcnt = (unsigned int*)(tilecnt + NTILES);
    uint2* recs     = (uint2*)(ovcnt + 16);
    uint2* ovrecs   = recs + (size_t)NTILES * SLOTS;

    hipMemsetAsync(ovcnt, 0, sizeof(unsigned int), stream);

    prep_kernel<<<BN / 4, 256, 0, stream>>>(score, sbf, mag);
    nes_kernel<<<(NTILES + 3) / 4, 256, 0, stream>>>(sbf, target, alpha, mag, nes_part,
                                                     recs, ovrecs, tilecnt, ovcnt);
    nes_reduce_kernel<<<BN / 256, 256, 0, stream>>>(nes_part, nes);
    pos_kernel<<<NTILES, 256, 0, stream>>>(recs, ovrecs, tilecnt, ovcnt, nes,
                                           part_sum, part_cnt);
    finalize_kernel<<<1, 256, 0, stream>>>(part_sum, part_cnt, out);
}